// Round 1
// baseline (1382.718 us; speedup 1.0000x reference)
//
#include <hip/hip_runtime.h>

// AdapterFusion: B=8 S=2048 N=8 D=768, T=50
// Algebraic rewrite: scores = key·(query@(Wq^T Wk) + bq@Wk) + query·(Wq^T bk) + bq·bk
// Pipeline: Wcomb -> bias vecs -> sb -> qk GEMM -> fused einsum/softmax/ctx -> Wv GEMM + residual

#define M_TOTAL 16384   // B*S
#define DDIM    768
#define NH      8

// ---------------- P: Wcomb[e,i] = sum_j Wq[j,e]*Wk[j,i]  (768x768x768, TN) ----------------
__global__ __launch_bounds__(256) void wcomb_kernel(const float* __restrict__ Wq,
                                                    const float* __restrict__ Wk,
                                                    float* __restrict__ Wcomb) {
    __shared__ __align__(16) float As[16][64];
    __shared__ __align__(16) float Bs[16][64];
    const int e0 = blockIdx.x * 64;
    const int i0 = blockIdx.y * 64;
    const int t  = threadIdx.x;
    const int tx = t % 16, ty = t / 16;
    float acc[4][4] = {};
    for (int k0 = 0; k0 < DDIM; k0 += 16) {
        const int r = t / 16, c4 = (t % 16) * 4;
        *(float4*)&As[r][c4] = *(const float4*)&Wq[(size_t)(k0 + r) * DDIM + e0 + c4];
        *(float4*)&Bs[r][c4] = *(const float4*)&Wk[(size_t)(k0 + r) * DDIM + i0 + c4];
        __syncthreads();
        #pragma unroll
        for (int kk = 0; kk < 16; ++kk) {
            float a[4], b[4];
            #pragma unroll
            for (int i = 0; i < 4; ++i) a[i] = As[kk][ty * 4 + i];
            #pragma unroll
            for (int j = 0; j < 4; ++j) b[j] = Bs[kk][tx * 4 + j];
            #pragma unroll
            for (int i = 0; i < 4; ++i)
                #pragma unroll
                for (int j = 0; j < 4; ++j) acc[i][j] = fmaf(a[i], b[j], acc[i][j]);
        }
        __syncthreads();
    }
    #pragma unroll
    for (int i = 0; i < 4; ++i) {
        float4 v = make_float4(acc[i][0], acc[i][1], acc[i][2], acc[i][3]);
        *(float4*)&Wcomb[(size_t)(e0 + ty * 4 + i) * DDIM + i0 + tx * 4] = v;
    }
}

// ---------------- bias vectors: bc = bq@Wk ; wqbk = bk@Wq ; bqbk = bq·bk ----------------
__global__ __launch_bounds__(256) void bias_kernel(const float* __restrict__ bq,
                                                   const float* __restrict__ Wk,
                                                   const float* __restrict__ bk,
                                                   const float* __restrict__ Wq,
                                                   float* __restrict__ bc,
                                                   float* __restrict__ wqbk,
                                                   float* __restrict__ bqbk) {
    __shared__ float red[256];
    const int b = blockIdx.x;
    const int t = threadIdx.x;
    if (b < 3) {
        const int i = b * 256 + t;
        float s = 0.f;
        for (int j = 0; j < DDIM; ++j) s = fmaf(bq[j], Wk[(size_t)j * DDIM + i], s);
        bc[i] = s;
    } else if (b < 6) {
        const int e = (b - 3) * 256 + t;
        float s = 0.f;
        for (int j = 0; j < DDIM; ++j) s = fmaf(bk[j], Wq[(size_t)j * DDIM + e], s);
        wqbk[e] = s;
    } else {
        float s = 0.f;
        for (int j = t; j < DDIM; j += 256) s = fmaf(bq[j], bk[j], s);
        red[t] = s; __syncthreads();
        for (int off = 128; off > 0; off >>= 1) {
            if (t < off) red[t] += red[t + off];
            __syncthreads();
        }
        if (t == 0) bqbk[0] = red[0];
    }
}

// ---------------- sb[m] = query[m,:]·wqbk + bqbk ----------------
__global__ __launch_bounds__(256) void sb_kernel(const float* __restrict__ query,
                                                 const float* __restrict__ wqbk,
                                                 const float* __restrict__ bqbk,
                                                 float* __restrict__ sb) {
    const int wave = threadIdx.x / 64, lane = threadIdx.x % 64;
    const int m = blockIdx.x * 4 + wave;
    float s = 0.f;
    #pragma unroll
    for (int i = 0; i < 12; ++i) {
        const int d = i * 64 + lane;
        s = fmaf(query[(size_t)m * DDIM + d], wqbk[d], s);
    }
    #pragma unroll
    for (int off = 32; off > 0; off >>= 1) s += __shfl_down(s, off, 64);
    if (lane == 0) sb[m] = s + bqbk[0];
}

// ---------------- 128x128 fp32 GEMM, K=768, M=16384, N=768 ----------------
// BMODE 0: C = A @ B + bias[col]            (B row-major K x N)   -> qk
// BMODE 1: C = A @ B^T + bias[row*768+col]  (B row-major N x K)   -> out (+residual)
template <int BMODE>
__global__ __launch_bounds__(256) void gemm128(const float* __restrict__ A,
                                               const float* __restrict__ B,
                                               const float* __restrict__ bias,
                                               float* __restrict__ C) {
    __shared__ __align__(16) float As[16][132];
    __shared__ __align__(16) float Bs[16][132];
    const int t  = threadIdx.x;
    const int n0 = blockIdx.x * 128;
    const int m0 = blockIdx.y * 128;
    const int tx = t % 16, ty = t / 16;
    float acc[8][8] = {};
    for (int k0 = 0; k0 < DDIM; k0 += 16) {
        {   // stage A (transpose into As[k][m])
            const int r = t / 4, c4 = (t % 4) * 4;
            #pragma unroll
            for (int h = 0; h < 2; ++h) {
                const float4 v = *(const float4*)&A[(size_t)(m0 + r + h * 64) * DDIM + k0 + c4];
                As[c4 + 0][r + h * 64] = v.x;
                As[c4 + 1][r + h * 64] = v.y;
                As[c4 + 2][r + h * 64] = v.z;
                As[c4 + 3][r + h * 64] = v.w;
            }
        }
        if (BMODE == 0) {  // B[k][n] direct
            const int c = t / 32, n4 = (t % 32) * 4;
            #pragma unroll
            for (int h = 0; h < 2; ++h)
                *(float4*)&Bs[c + h * 8][n4] =
                    *(const float4*)&B[(size_t)(k0 + c + h * 8) * DDIM + n0 + n4];
        } else {           // B[n][k] -> transpose into Bs[k][n]
            const int n = t / 4, c4 = (t % 4) * 4;
            #pragma unroll
            for (int h = 0; h < 2; ++h) {
                const float4 v = *(const float4*)&B[(size_t)(n0 + n + h * 64) * DDIM + k0 + c4];
                Bs[c4 + 0][n + h * 64] = v.x;
                Bs[c4 + 1][n + h * 64] = v.y;
                Bs[c4 + 2][n + h * 64] = v.z;
                Bs[c4 + 3][n + h * 64] = v.w;
            }
        }
        __syncthreads();
        #pragma unroll
        for (int kk = 0; kk < 16; ++kk) {
            float a[8], b[8];
            #pragma unroll
            for (int i = 0; i < 8; ++i) a[i] = As[kk][ty * 8 + i];
            #pragma unroll
            for (int j = 0; j < 8; ++j) b[j] = Bs[kk][tx * 8 + j];
            #pragma unroll
            for (int i = 0; i < 8; ++i)
                #pragma unroll
                for (int j = 0; j < 8; ++j) acc[i][j] = fmaf(a[i], b[j], acc[i][j]);
        }
        __syncthreads();
    }
    #pragma unroll
    for (int i = 0; i < 8; ++i) {
        const int row = m0 + ty * 8 + i;
        #pragma unroll
        for (int j4 = 0; j4 < 8; j4 += 4) {
            const int col = n0 + tx * 8 + j4;
            float4 v;
            if (BMODE == 0) {
                v = make_float4(acc[i][j4 + 0] + bias[col + 0],
                                acc[i][j4 + 1] + bias[col + 1],
                                acc[i][j4 + 2] + bias[col + 2],
                                acc[i][j4 + 3] + bias[col + 3]);
            } else {
                const float4 rv = *(const float4*)&bias[(size_t)row * DDIM + col];
                v = make_float4(acc[i][j4 + 0] + rv.x, acc[i][j4 + 1] + rv.y,
                                acc[i][j4 + 2] + rv.z, acc[i][j4 + 3] + rv.w);
            }
            *(float4*)&C[(size_t)row * DDIM + col] = v;
        }
    }
}

// ---------------- fused scores/softmax/ctx: one block (192 thr) per (b,s) row ----------------
__global__ __launch_bounds__(192) void mix_kernel(const float* __restrict__ qk,
                                                  const float* __restrict__ sb,
                                                  const float* __restrict__ key,
                                                  const float* __restrict__ value,
                                                  float* __restrict__ probs,
                                                  float* __restrict__ ctx) {
    __shared__ float red[3][8];
    const int m = blockIdx.x;
    const int t = threadIdx.x;           // 192 threads * float4 = 768
    const int wave = t / 64, lane = t % 64;
    const float4 q4 = *(const float4*)&qk[(size_t)m * DDIM + t * 4];
    float part[NH];
    #pragma unroll
    for (int n = 0; n < NH; ++n) {
        const float4 k4 = *(const float4*)&key[((size_t)m * NH + n) * DDIM + t * 4];
        part[n] = q4.x * k4.x + q4.y * k4.y + q4.z * k4.z + q4.w * k4.w;
    }
    #pragma unroll
    for (int n = 0; n < NH; ++n) {
        float s = part[n];
        #pragma unroll
        for (int off = 32; off > 0; off >>= 1) s += __shfl_down(s, off, 64);
        part[n] = s;
    }
    if (lane == 0) {
        #pragma unroll
        for (int n = 0; n < NH; ++n) red[wave][n] = part[n];
    }
    __syncthreads();
    const float sbm = sb[m];
    float sc[NH], mx = -1e30f;
    #pragma unroll
    for (int n = 0; n < NH; ++n) {
        sc[n] = (red[0][n] + red[1][n] + red[2][n] + sbm) * (1.0f / 50.0f);
        mx = fmaxf(mx, sc[n]);
    }
    float p[NH], den = 0.f;
    #pragma unroll
    for (int n = 0; n < NH; ++n) { p[n] = __expf(sc[n] - mx); den += p[n]; }
    const float inv = 1.0f / den;
    #pragma unroll
    for (int n = 0; n < NH; ++n) p[n] *= inv;
    if (t < NH) probs[(size_t)m * NH + t] = p[t];
    float4 c4 = make_float4(0.f, 0.f, 0.f, 0.f);
    #pragma unroll
    for (int n = 0; n < NH; ++n) {
        const float4 v4 = *(const float4*)&value[((size_t)m * NH + n) * DDIM + t * 4];
        c4.x = fmaf(p[n], v4.x, c4.x);
        c4.y = fmaf(p[n], v4.y, c4.y);
        c4.z = fmaf(p[n], v4.z, c4.z);
        c4.w = fmaf(p[n], v4.w, c4.w);
    }
    *(float4*)&ctx[(size_t)m * DDIM + t * 4] = c4;
}

extern "C" void kernel_launch(void* const* d_in, const int* in_sizes, int n_in,
                              void* d_out, int out_size, void* d_ws, size_t ws_size,
                              hipStream_t stream) {
    const float* query    = (const float*)d_in[0];
    const float* key      = (const float*)d_in[1];
    const float* value    = (const float*)d_in[2];
    const float* residual = (const float*)d_in[3];
    const float* Wq       = (const float*)d_in[4];
    const float* bq       = (const float*)d_in[5];
    const float* Wk       = (const float*)d_in[6];
    const float* bk       = (const float*)d_in[7];
    const float* Wv       = (const float*)d_in[8];

    float* out   = (float*)d_out;
    float* probs = out;                // [16384 x 8]
    float* qk    = out + 131072;       // reuse ctx output region as qk scratch

    char* ws = (char*)d_ws;
    float* Wcomb = (float*)(ws + 0);                 // 2,359,296 B
    float* bc    = (float*)(ws + 2359296);           // 3,072 B
    float* wqbk  = (float*)(ws + 2362368);           // 3,072 B
    float* bqbk  = (float*)(ws + 2365440);           // 16 B
    float* sb    = (float*)(ws + 2365456);           // 65,536 B
    float* ctx   = (float*)(ws + 2430992);           // 50,331,648 B  (total ~52.8 MB)

    hipLaunchKernelGGL(wcomb_kernel, dim3(12, 12), dim3(256), 0, stream, Wq, Wk, Wcomb);
    hipLaunchKernelGGL(bias_kernel, dim3(7), dim3(256), 0, stream, bq, Wk, bk, Wq, bc, wqbk, bqbk);
    hipLaunchKernelGGL(sb_kernel, dim3(4096), dim3(256), 0, stream, query, wqbk, bqbk, sb);
    hipLaunchKernelGGL((gemm128<0>), dim3(6, 128), dim3(256), 0, stream, query, Wcomb, bc, qk);
    hipLaunchKernelGGL(mix_kernel, dim3(16384), dim3(192), 0, stream, qk, sb, key, value, probs, ctx);
    hipLaunchKernelGGL((gemm128<1>), dim3(6, 128), dim3(256), 0, stream, ctx, Wv, residual, out + 131072);
}